// Round 7
// baseline (33.865 us; speedup 1.0000x reference)
//
#include <hip/hip_runtime.h>
#include <hip/hip_bf16.h>
#include <math.h>

// Problem constants: B=1, C=256, H=W=50, N=256 boxes, OUT=7
#define RC    256
#define RH    50
#define RW    50
#define RN    256
#define ROUT  7
#define NBINS 49
#define HW    (RH * RW)

#define BOUNDS_OFF (3u << 20)   // bounds table at d_ws + 3 MB (featT is 2.56 MB)

// ---------- kernel 1: LDS-tiled transpose (blocks 0..159) + bounds precompute
// (blocks 160..172).  featT[hw][c] = feat[c][hw];  bounds[n*49+b] = packed u8x4.
__global__ void __launch_bounds__(256)
prep_kernel(const float* __restrict__ feat,
            const float* __restrict__ boxes,
            const int* __restrict__ image_size_p,
            float* __restrict__ featT,
            unsigned int* __restrict__ bounds) {
    if (blockIdx.x < 160) {
        __shared__ float tile[64][65];
        int ct = blockIdx.x & 3;
        int ht = blockIdx.x >> 2;
        int c0 = ct * 64;
        int h0 = ht * 64;
        int col  = threadIdx.x & 63;
        int row4 = threadIdx.x >> 6;
        #pragma unroll
        for (int i = 0; i < 16; ++i) {
            int r  = row4 + 4 * i;
            int hw = h0 + col;
            if (hw < HW)
                tile[r][col] = feat[(c0 + r) * HW + hw];   // coalesced along hw
        }
        __syncthreads();
        #pragma unroll
        for (int i = 0; i < 16; ++i) {
            int r  = row4 + 4 * i;
            int hw = h0 + r;
            if (hw < HW)
                featT[hw * RC + c0 + col] = tile[col][r];  // coalesced along c
        }
        return;
    }

    // ---- bounds blocks: 13*256 threads; thread -> (box n, bin-quad g) ----
    int idx = (blockIdx.x - 160) * 256 + threadIdx.x;   // 0..3327
    int n = idx & 255;
    int g = idx >> 8;                                   // 0..12

    float im = (float)(*image_size_p);
    float scale_w = (float)RW / im;
    float scale_h = (float)RH / im;

    float bx = boxes[n * 4 + 0];
    float by = boxes[n * 4 + 1];
    float bw = boxes[n * 4 + 2];
    float bh = boxes[n * 4 + 3];
    bool bad = (bw <= 0.0f) || (bh <= 0.0f);

    float x1f = (bad ? 0.25f * im : bx) * scale_w;
    float x2f = (bad ? 0.75f * im : bx + bw) * scale_w;
    float y1f = (bad ? 0.25f * im : by) * scale_h;
    float y2f = (bad ? 0.75f * im : by + bh) * scale_h;

    int x1 = max(0, (int)x1f);
    int y1 = max(0, (int)y1f);
    int x2 = min(RW, (int)x2f + 1);
    int y2 = min(RH, (int)y2f + 1);
    if (x2 <= x1 + 1) x2 = min(x1 + 2, RW);
    if (y2 <= y1 + 1) y2 = min(y1 + 2, RH);
    x1 = min(max(x1, 0), RW - 2);
    y1 = min(max(y1, 0), RH - 2);
    x2 = max(x1 + 1, min(x2, RW));
    y2 = max(y1 + 1, min(y2, RH));

    int szx = x2 - x1;
    int szy = y2 - y1;

    #pragma unroll
    for (int k = 0; k < 4; ++k) {
        int b = g * 4 + k;
        if (b < NBINS) {
            int ky = b / ROUT;
            int kx = b - ky * ROUT;
            unsigned sx = x1 + (kx * szx) / ROUT;
            unsigned ex = x1 + ((kx + 1) * szx + ROUT - 1) / ROUT;
            unsigned sy = y1 + (ky * szy) / ROUT;
            unsigned ey = y1 + ((ky + 1) * szy + ROUT - 1) / ROUT;
            bounds[n * NBINS + b] = sx | (ex << 8) | (sy << 16) | (ey << 24);
        }
    }
}

// ---------- kernel 2: pool. block = (box, bin-quad); wave = one bin x 256 ch ----
__global__ void __launch_bounds__(256)
pool_kernel(const float* __restrict__ featT,
            const unsigned int* __restrict__ bounds,
            float* __restrict__ out) {
    __shared__ float res[RC * 5];   // [c][bin-in-quad], stride 5 -> conflict-free

    const int bid = blockIdx.x;
    const int n   = bid / 13;
    const int bq  = bid - n * 13;
    const int t    = threadIdx.x;
    const int lane = t & 63;
    const int w    = __builtin_amdgcn_readfirstlane(t >> 6);  // wave id as SGPR

    const int bin = bq * 4 + w;
    if (bin < NBINS) {
        const unsigned bb = bounds[n * NBINS + bin];   // uniform -> s_load
        const int sx = bb & 255;
        const int ex = (bb >> 8) & 255;
        const int sy = (bb >> 16) & 255;
        const int ey = bb >> 24;

        float m0 = -INFINITY, m1 = -INFINITY, m2 = -INFINITY, m3 = -INFINITY;
        for (int y = sy; y < ey; ++y) {
            const float* __restrict__ rp = featT + (y * RW) * RC + lane;
            for (int x = sx; x < ex; ++x) {
                const float* __restrict__ p = rp + x * RC;
                float v0 = p[0];            // 4 independent 256B wave loads
                float v1 = p[64];
                float v2 = p[128];
                float v3 = p[192];
                m0 = fmaxf(m0, v0);
                m1 = fmaxf(m1, v1);
                m2 = fmaxf(m2, v2);
                m3 = fmaxf(m3, v3);
            }
        }
        res[(lane       ) * 5 + w] = m0;
        res[(lane +  64) * 5 + w] = m1;
        res[(lane + 128) * 5 + w] = m2;
        res[(lane + 192) * 5 + w] = m3;
    }
    __syncthreads();

    // writeout: thread t = channel; 4 consecutive bins -> 16B runs, stride 196B
    const int obase = (n * RC + t) * NBINS + bq * 4;
    #pragma unroll
    for (int b = 0; b < 4; ++b) {
        if (bq * 4 + b < NBINS)
            out[obase + b] = res[t * 5 + b];
    }
}

extern "C" void kernel_launch(void* const* d_in, const int* in_sizes, int n_in,
                              void* d_out, int out_size, void* d_ws, size_t ws_size,
                              hipStream_t stream) {
    const float* feat  = (const float*)d_in[0];
    const float* boxes = (const float*)d_in[1];
    const int* im_sz   = (const int*)d_in[2];
    float* out   = (float*)d_out;
    float* featT = (float*)d_ws;
    unsigned int* bounds = (unsigned int*)((char*)d_ws + BOUNDS_OFF);

    prep_kernel<<<173, 256, 0, stream>>>(feat, boxes, im_sz, featT, bounds);
    pool_kernel<<<RN * 13, 256, 0, stream>>>(featT, bounds, out);
}